// Round 1
// baseline (452.149 us; speedup 1.0000x reference)
//
#include <hip/hip_runtime.h>
#include <hip/hip_bf16.h>
#include <cstdint>

#define NN 50000
#define NEDGE 800000
#define IND 256
#define NH 8
#define DHH 32
#define NET 8
#define LALPHA 0.2f
#define OD 256
#define CD 512

typedef __attribute__((ext_vector_type(8))) short short8;
typedef __attribute__((ext_vector_type(4))) float f32x4;

__device__ __forceinline__ unsigned short f2bf(float x) {
  union { float f; unsigned u; } v; v.f = x;
  unsigned r = v.u + 0x7FFFu + ((v.u >> 16) & 1u);
  return (unsigned short)(r >> 16);
}
__device__ __forceinline__ float bf2f(unsigned short u) {
  union { unsigned u; float f; } v; v.u = ((unsigned)u) << 16;
  return v.f;
}

// ---- cast feat (N x 256 f32 -> bf16), 4 elems/thread ----
__global__ __launch_bounds__(256) void k_cast_feat(const float* __restrict__ f,
                                                   unsigned short* __restrict__ fb) {
  size_t i = (size_t)blockIdx.x * 256 + threadIdx.x;
  size_t base = i * 4;
  if (base < (size_t)NN * IND) {
    float4 v = *reinterpret_cast<const float4*>(f + base);
    ushort4 o;
    o.x = f2bf(v.x); o.y = f2bf(v.y); o.z = f2bf(v.z); o.w = f2bf(v.w);
    *reinterpret_cast<ushort4*>(fb + base) = o;
  }
}

// ---- build W^T concat (512 x 256 bf16): Wtb[c][k] = (c<256? Wfc : Wres)[k][c%256] ----
__global__ __launch_bounds__(256) void k_cast_w(const float* __restrict__ Wfc,
                                                const float* __restrict__ Wres,
                                                unsigned short* __restrict__ Wtb) {
  int id = blockIdx.x * 256 + threadIdx.x;  // 512*256 threads
  int k = id >> 9;
  int c = id & 511;
  float v = (c < OD) ? Wfc[k * OD + c] : Wres[k * OD + (c - OD)];
  Wtb[(size_t)c * IND + k] = f2bf(v);
}

// ---- bf16 MFMA GEMM: [NN x 256] @ [256 x 512] ; cols<256 -> Hb (bf16, +b_fc), cols>=256 -> R=d_out (f32, +b_res)
__global__ __launch_bounds__(256) void k_gemm(const unsigned short* __restrict__ A,
                                              const unsigned short* __restrict__ Bt,
                                              const float* __restrict__ bfc,
                                              const float* __restrict__ bres,
                                              unsigned short* __restrict__ Hb,
                                              float* __restrict__ R) {
  __shared__ unsigned short As[64][40];  // +8 bf16 pad
  __shared__ unsigned short Bs[64][40];  // B^T tile: [col][k]
  int bm = blockIdx.x, bn = blockIdx.y;
  int tid = threadIdx.x;
  int wave = tid >> 6, lane = tid & 63;
  int row0 = bm * 64, col0 = bn * 64;

  int ar = tid >> 2;          // 0..63
  int ak = (tid & 3) * 8;     // 0,8,16,24

  f32x4 acc[4];
#pragma unroll
  for (int i = 0; i < 4; ++i) acc[i] = (f32x4){0.f, 0.f, 0.f, 0.f};

  for (int k0 = 0; k0 < IND; k0 += 32) {
    int grow = row0 + ar;
    short8 av = {};
    if (grow < NN)
      av = *reinterpret_cast<const short8*>(A + (size_t)grow * IND + k0 + ak);
    *reinterpret_cast<short8*>(&As[ar][ak]) = av;
    short8 bv = *reinterpret_cast<const short8*>(Bt + (size_t)(col0 + ar) * IND + k0 + ak);
    *reinterpret_cast<short8*>(&Bs[ar][ak]) = bv;
    __syncthreads();
    short8 a = *reinterpret_cast<const short8*>(&As[wave * 16 + (lane & 15)][(lane >> 4) * 8]);
#pragma unroll
    for (int nf = 0; nf < 4; ++nf) {
      short8 b = *reinterpret_cast<const short8*>(&Bs[nf * 16 + (lane & 15)][(lane >> 4) * 8]);
      acc[nf] = __builtin_amdgcn_mfma_f32_16x16x32_bf16(a, b, acc[nf], 0, 0, 0);
    }
    __syncthreads();
  }

  int rl = wave * 16 + ((lane >> 4) * 4);
  int cl = lane & 15;
#pragma unroll
  for (int nf = 0; nf < 4; ++nf) {
    int gcol = col0 + nf * 16 + cl;
#pragma unroll
    for (int r = 0; r < 4; ++r) {
      int grow = row0 + rl + r;
      if (grow < NN) {
        float vv = acc[nf][r];
        if (gcol < OD) Hb[(size_t)grow * OD + gcol] = f2bf(vv + bfc[gcol]);
        else R[(size_t)grow * OD + (gcol - OD)] = vv + bres[gcol - OD];
      }
    }
  }
}

// ---- per-node attention scores: s_src[n,h], s_dst[n,h] ----
__global__ __launch_bounds__(256) void k_scores(const unsigned short* __restrict__ Hb,
                                                const float* __restrict__ attn,
                                                float* __restrict__ ssrc,
                                                float* __restrict__ sdst) {
  int v = blockIdx.x, t = threadIdx.x;
  int h = t >> 5, d = t & 31;
  float val = bf2f(Hb[(size_t)v * OD + t]);
  float p1 = val * attn[h * 96 + d];
  float p2 = val * attn[h * 96 + 32 + d];
#pragma unroll
  for (int off = 16; off; off >>= 1) {
    p1 += __shfl_xor(p1, off, 32);
    p2 += __shfl_xor(p2, off, 32);
  }
  if (d == 0) { ssrc[v * NH + h] = p1; sdst[v * NH + h] = p2; }
}

// ---- s_e[et,h] (only 64 values) ----
__global__ void k_se(const float* __restrict__ ee, const float* __restrict__ attn,
                     float* __restrict__ se) {
  int t = threadIdx.x;
  int h = t >> 5, d = t & 31;
  float ae = attn[h * 96 + 64 + d];
  for (int et = 0; et < NET; ++et) {
    float p = ee[et * OD + t] * ae;
#pragma unroll
    for (int off = 16; off; off >>= 1) p += __shfl_xor(p, off, 32);
    if (d == 0) se[et * NH + h] = p;
  }
}

// ---- CSR build ----
__global__ __launch_bounds__(256) void k_hist(const int* __restrict__ dst, int* __restrict__ cnt) {
  int e = blockIdx.x * 256 + threadIdx.x;
  if (e < NEDGE) atomicAdd(&cnt[dst[e]], 1);
}

__global__ void k_scan(const int* __restrict__ cnt, int* __restrict__ off) {
  __shared__ int part[1024];
  __shared__ int total;
  int tid = threadIdx.x;
  const int chunk = (NN + 1023) / 1024;
  int s = tid * chunk, e = min(s + chunk, NN);
  int sum = 0;
  for (int i = s; i < e; ++i) sum += cnt[i];
  part[tid] = sum;
  __syncthreads();
  if (tid == 0) {
    int run = 0;
    for (int i = 0; i < 1024; ++i) { int v = part[i]; part[i] = run; run += v; }
    total = run;
  }
  __syncthreads();
  int run = part[tid];
  for (int i = s; i < e; ++i) { off[i] = run; run += cnt[i]; }
  if (tid == 0) off[NN] = total;
}

__global__ __launch_bounds__(256) void k_scatter(const int* __restrict__ src,
                                                 const int* __restrict__ dst,
                                                 const int* __restrict__ ety,
                                                 const int* __restrict__ off,
                                                 int* __restrict__ cur,
                                                 int* __restrict__ packed) {
  int e = blockIdx.x * 256 + threadIdx.x;
  if (e < NEDGE) {
    int d = dst[e];
    int pos = off[d] + atomicAdd(&cur[d], 1);
    packed[pos] = src[e] | (ety[e] << 16);   // src < 65536, et < 8
  }
}

// ---- per-node online-softmax aggregation; adds residual (already in out), ELU ----
__global__ __launch_bounds__(256) void k_aggregate(const unsigned short* __restrict__ Hb,
                                                   const float* __restrict__ ssrc,
                                                   const float* __restrict__ sdst,
                                                   const float* __restrict__ se,
                                                   const int* __restrict__ off,
                                                   const int* __restrict__ packed,
                                                   float* __restrict__ out) {
  int v = blockIdx.x, t = threadIdx.x;
  int h = t >> 5;
  int lo = off[v], hi = off[v + 1];
  float sd = sdst[v * NH + h];
  float m = -INFINITY, ssum = 0.f, acc = 0.f;
  for (int i = lo; i < hi; ++i) {
    int pk = packed[i];
    int u = pk & 0xFFFF;
    int et = pk >> 16;
    float sc = ssrc[u * NH + h] + sd + se[et * NH + h];
    sc = sc > 0.f ? sc : LALPHA * sc;
    float hv = bf2f(Hb[(size_t)u * OD + t]);
    float mn = fmaxf(m, sc);
    float scale = __expf(m - mn);   // first iter: exp(-inf)=0
    float p = __expf(sc - mn);
    ssum = ssum * scale + p;
    acc = acc * scale + p * hv;
    m = mn;
  }
  size_t oi = (size_t)v * OD + t;
  float r = out[oi];
  float o = (hi > lo) ? (acc / ssum + r) : r;
  out[oi] = (o > 0.f) ? o : expm1f(o);
}

extern "C" void kernel_launch(void* const* d_in, const int* in_sizes, int n_in,
                              void* d_out, int out_size, void* d_ws, size_t ws_size,
                              hipStream_t stream) {
  const float* feat = (const float*)d_in[0];
  const int* src = (const int*)d_in[1];
  const int* dst = (const int*)d_in[2];
  const int* ety = (const int*)d_in[3];
  const float* Wfc = (const float*)d_in[4];
  const float* bfc = (const float*)d_in[5];
  const float* ee = (const float*)d_in[6];
  const float* attn = (const float*)d_in[7];
  const float* Wres = (const float*)d_in[8];
  const float* bres = (const float*)d_in[9];
  float* out = (float*)d_out;

  char* w = (char*)d_ws;
  unsigned short* featb = (unsigned short*)w; w += (size_t)NN * IND * 2;
  unsigned short* Wtb   = (unsigned short*)w; w += (size_t)CD * IND * 2;
  unsigned short* Hb    = (unsigned short*)w; w += (size_t)NN * OD * 2;
  float* ssrc = (float*)w; w += (size_t)NN * NH * 4;
  float* sdst = (float*)w; w += (size_t)NN * NH * 4;
  float* se   = (float*)w; w += 64 * 4;
  int* cnt    = (int*)w; w += (size_t)NN * 4;
  int* cur    = (int*)w; w += (size_t)NN * 4;   // adjacent to cnt: one memset
  int* off    = (int*)w; w += (size_t)(NN + 1) * 4;
  int* packed = (int*)w; w += (size_t)NEDGE * 4;

  hipMemsetAsync(cnt, 0, (size_t)NN * 2 * 4, stream);

  k_cast_feat<<<(NN * IND / 4 + 255) / 256, 256, 0, stream>>>(feat, featb);
  k_cast_w<<<(CD * IND) / 256, 256, 0, stream>>>(Wfc, Wres, Wtb);
  dim3 gg((NN + 63) / 64, CD / 64);
  k_gemm<<<gg, 256, 0, stream>>>(featb, Wtb, bfc, bres, Hb, out);
  k_scores<<<NN, 256, 0, stream>>>(Hb, attn, ssrc, sdst);
  k_se<<<1, 256, 0, stream>>>(ee, attn, se);
  k_hist<<<(NEDGE + 255) / 256, 256, 0, stream>>>(dst, cnt);
  k_scan<<<1, 1024, 0, stream>>>(cnt, off);
  k_scatter<<<(NEDGE + 255) / 256, 256, 0, stream>>>(src, dst, ety, off, cur, packed);
  k_aggregate<<<NN, 256, 0, stream>>>(Hb, ssrc, sdst, se, off, packed, out);
}

// Round 2
// 390.561 us; speedup vs baseline: 1.1577x; 1.1577x over previous
//
#include <hip/hip_runtime.h>
#include <hip/hip_bf16.h>
#include <cstdint>

#define NN 50000
#define NEDGE 800000
#define IND 256
#define NH 8
#define DHH 32
#define NET 8
#define LALPHA 0.2f
#define OD 256
#define CD 512

typedef __attribute__((ext_vector_type(8))) short short8;
typedef __attribute__((ext_vector_type(4))) float f32x4;

__device__ __forceinline__ unsigned short f2bf(float x) {
  union { float f; unsigned u; } v; v.f = x;
  unsigned r = v.u + 0x7FFFu + ((v.u >> 16) & 1u);
  return (unsigned short)(r >> 16);
}
__device__ __forceinline__ float bf2f(unsigned short u) {
  union { unsigned u; float f; } v; v.u = ((unsigned)u) << 16;
  return v.f;
}

// ---- cast feat (N x 256 f32 -> bf16), 4 elems/thread ----
__global__ __launch_bounds__(256) void k_cast_feat(const float* __restrict__ f,
                                                   unsigned short* __restrict__ fb) {
  size_t i = (size_t)blockIdx.x * 256 + threadIdx.x;
  size_t base = i * 4;
  if (base < (size_t)NN * IND) {
    float4 v = *reinterpret_cast<const float4*>(f + base);
    ushort4 o;
    o.x = f2bf(v.x); o.y = f2bf(v.y); o.z = f2bf(v.z); o.w = f2bf(v.w);
    *reinterpret_cast<ushort4*>(fb + base) = o;
  }
}

// ---- build W^T concat (512 x 256 bf16) ----
__global__ __launch_bounds__(256) void k_cast_w(const float* __restrict__ Wfc,
                                                const float* __restrict__ Wres,
                                                unsigned short* __restrict__ Wtb) {
  int id = blockIdx.x * 256 + threadIdx.x;  // 512*256 threads
  int k = id >> 9;
  int c = id & 511;
  float v = (c < OD) ? Wfc[k * OD + c] : Wres[k * OD + (c - OD)];
  Wtb[(size_t)c * IND + k] = f2bf(v);
}

// ---- bf16 MFMA GEMM: [NN x 256] @ [256 x 512] ----
__global__ __launch_bounds__(256) void k_gemm(const unsigned short* __restrict__ A,
                                              const unsigned short* __restrict__ Bt,
                                              const float* __restrict__ bfc,
                                              const float* __restrict__ bres,
                                              unsigned short* __restrict__ Hb,
                                              float* __restrict__ R) {
  __shared__ unsigned short As[64][40];
  __shared__ unsigned short Bs[64][40];
  int bm = blockIdx.x, bn = blockIdx.y;
  int tid = threadIdx.x;
  int wave = tid >> 6, lane = tid & 63;
  int row0 = bm * 64, col0 = bn * 64;

  int ar = tid >> 2;
  int ak = (tid & 3) * 8;

  f32x4 acc[4];
#pragma unroll
  for (int i = 0; i < 4; ++i) acc[i] = (f32x4){0.f, 0.f, 0.f, 0.f};

  for (int k0 = 0; k0 < IND; k0 += 32) {
    int grow = row0 + ar;
    short8 av = {};
    if (grow < NN)
      av = *reinterpret_cast<const short8*>(A + (size_t)grow * IND + k0 + ak);
    *reinterpret_cast<short8*>(&As[ar][ak]) = av;
    short8 bv = *reinterpret_cast<const short8*>(Bt + (size_t)(col0 + ar) * IND + k0 + ak);
    *reinterpret_cast<short8*>(&Bs[ar][ak]) = bv;
    __syncthreads();
    short8 a = *reinterpret_cast<const short8*>(&As[wave * 16 + (lane & 15)][(lane >> 4) * 8]);
#pragma unroll
    for (int nf = 0; nf < 4; ++nf) {
      short8 b = *reinterpret_cast<const short8*>(&Bs[nf * 16 + (lane & 15)][(lane >> 4) * 8]);
      acc[nf] = __builtin_amdgcn_mfma_f32_16x16x32_bf16(a, b, acc[nf], 0, 0, 0);
    }
    __syncthreads();
  }

  int rl = wave * 16 + ((lane >> 4) * 4);
  int cl = lane & 15;
#pragma unroll
  for (int nf = 0; nf < 4; ++nf) {
    int gcol = col0 + nf * 16 + cl;
#pragma unroll
    for (int r = 0; r < 4; ++r) {
      int grow = row0 + rl + r;
      if (grow < NN) {
        float vv = acc[nf][r];
        if (gcol < OD) Hb[(size_t)grow * OD + gcol] = f2bf(vv + bfc[gcol]);
        else R[(size_t)grow * OD + (gcol - OD)] = vv + bres[gcol - OD];
      }
    }
  }
}

// ---- per-node attention scores ----
__global__ __launch_bounds__(256) void k_scores(const unsigned short* __restrict__ Hb,
                                                const float* __restrict__ attn,
                                                float* __restrict__ ssrc,
                                                float* __restrict__ sdst) {
  int v = blockIdx.x, t = threadIdx.x;
  int h = t >> 5, d = t & 31;
  float val = bf2f(Hb[(size_t)v * OD + t]);
  float p1 = val * attn[h * 96 + d];
  float p2 = val * attn[h * 96 + 32 + d];
#pragma unroll
  for (int off = 16; off; off >>= 1) {
    p1 += __shfl_xor(p1, off, 32);
    p2 += __shfl_xor(p2, off, 32);
  }
  if (d == 0) { ssrc[v * NH + h] = p1; sdst[v * NH + h] = p2; }
}

// ---- s_e[et,h] ----
__global__ void k_se(const float* __restrict__ ee, const float* __restrict__ attn,
                     float* __restrict__ se) {
  int t = threadIdx.x;
  int h = t >> 5, d = t & 31;
  float ae = attn[h * 96 + 64 + d];
  for (int et = 0; et < NET; ++et) {
    float p = ee[et * OD + t] * ae;
#pragma unroll
    for (int off = 16; off; off >>= 1) p += __shfl_xor(p, off, 32);
    if (d == 0) se[et * NH + h] = p;
  }
}

// ---- CSR build ----
__global__ __launch_bounds__(256) void k_hist(const int* __restrict__ dst, int* __restrict__ cnt) {
  int e = blockIdx.x * 256 + threadIdx.x;
  if (e < NEDGE) atomicAdd(&cnt[dst[e]], 1);
}

__global__ void k_scan(const int* __restrict__ cnt, int* __restrict__ off) {
  __shared__ int part[1024];
  __shared__ int total;
  int tid = threadIdx.x;
  const int chunk = (NN + 1023) / 1024;
  int s = tid * chunk, e = min(s + chunk, NN);
  int sum = 0;
  for (int i = s; i < e; ++i) sum += cnt[i];
  part[tid] = sum;
  __syncthreads();
  if (tid == 0) {
    int run = 0;
    for (int i = 0; i < 1024; ++i) { int v = part[i]; part[i] = run; run += v; }
    total = run;
  }
  __syncthreads();
  int run = part[tid];
  for (int i = s; i < e; ++i) { off[i] = run; run += cnt[i]; }
  if (tid == 0) off[NN] = total;
}

// ---- edge-parallel: CSR scatter + per-edge softmax numerators (8 heads, bf16) ----
__global__ __launch_bounds__(256) void k_edge(const int* __restrict__ src,
                                              const int* __restrict__ dst,
                                              const int* __restrict__ ety,
                                              const float* __restrict__ ssrc,
                                              const float* __restrict__ sdst,
                                              const float* __restrict__ se,
                                              const int* __restrict__ off,
                                              int* __restrict__ cur,
                                              int* __restrict__ packed,
                                              unsigned short* __restrict__ pw) {
  __shared__ float sse[64];
  int tid = threadIdx.x;
  if (tid < 64) sse[tid] = se[tid];
  __syncthreads();
  int e = blockIdx.x * 256 + tid;
  if (e >= NEDGE) return;
  int u = src[e], v = dst[e], et = ety[e];
  int pos = off[v] + atomicAdd(&cur[v], 1);
  packed[pos] = u;
  float4 a0 = *reinterpret_cast<const float4*>(ssrc + (size_t)u * NH);
  float4 a1 = *reinterpret_cast<const float4*>(ssrc + (size_t)u * NH + 4);
  float4 b0 = *reinterpret_cast<const float4*>(sdst + (size_t)v * NH);
  float4 b1 = *reinterpret_cast<const float4*>(sdst + (size_t)v * NH + 4);
  float sa[8] = {a0.x + b0.x, a0.y + b0.y, a0.z + b0.z, a0.w + b0.w,
                 a1.x + b1.x, a1.y + b1.y, a1.z + b1.z, a1.w + b1.w};
  ushort4 o0, o1;
  unsigned short w8[8];
#pragma unroll
  for (int h = 0; h < 8; ++h) {
    float s = sa[h] + sse[et * NH + h];
    s = s > 0.f ? s : LALPHA * s;
    w8[h] = f2bf(__expf(s));   // scores are O(2): exp is safe without max-sub
  }
  o0.x = w8[0]; o0.y = w8[1]; o0.z = w8[2]; o0.w = w8[3];
  o1.x = w8[4]; o1.y = w8[5]; o1.z = w8[6]; o1.w = w8[7];
  *reinterpret_cast<ushort4*>(pw + (size_t)pos * NH) = o0;
  *reinterpret_cast<ushort4*>(pw + (size_t)pos * NH + 4) = o1;
}

// ---- per-node aggregation: acc += p*h, dsum += p; then /dsum + residual, ELU ----
__global__ __launch_bounds__(256) void k_agg2(const unsigned short* __restrict__ Hb,
                                              const int* __restrict__ off,
                                              const int* __restrict__ packed,
                                              const unsigned short* __restrict__ pw,
                                              float* __restrict__ out) {
  int v = blockIdx.x, t = threadIdx.x;
  int h = t >> 5;
  int lo = off[v], hi = off[v + 1];
  float acc = 0.f, dsum = 0.f;
  int i = lo;
  for (; i + 2 <= hi; i += 2) {
    int u0 = packed[i], u1 = packed[i + 1];
    float p0 = bf2f(pw[(size_t)i * NH + h]);
    float p1 = bf2f(pw[(size_t)(i + 1) * NH + h]);
    float h0 = bf2f(Hb[(size_t)u0 * OD + t]);
    float h1 = bf2f(Hb[(size_t)u1 * OD + t]);
    acc = fmaf(p0, h0, acc);
    acc = fmaf(p1, h1, acc);
    dsum += p0 + p1;
  }
  if (i < hi) {
    int u0 = packed[i];
    float p0 = bf2f(pw[(size_t)i * NH + h]);
    float h0 = bf2f(Hb[(size_t)u0 * OD + t]);
    acc = fmaf(p0, h0, acc);
    dsum += p0;
  }
  size_t oi = (size_t)v * OD + t;
  float r = out[oi];
  float o = (dsum > 0.f) ? (acc / dsum + r) : r;
  out[oi] = (o > 0.f) ? o : expm1f(o);
}

extern "C" void kernel_launch(void* const* d_in, const int* in_sizes, int n_in,
                              void* d_out, int out_size, void* d_ws, size_t ws_size,
                              hipStream_t stream) {
  const float* feat = (const float*)d_in[0];
  const int* src = (const int*)d_in[1];
  const int* dst = (const int*)d_in[2];
  const int* ety = (const int*)d_in[3];
  const float* Wfc = (const float*)d_in[4];
  const float* bfc = (const float*)d_in[5];
  const float* ee = (const float*)d_in[6];
  const float* attn = (const float*)d_in[7];
  const float* Wres = (const float*)d_in[8];
  const float* bres = (const float*)d_in[9];
  float* out = (float*)d_out;

  char* w = (char*)d_ws;
  unsigned short* featb = (unsigned short*)w; w += (size_t)NN * IND * 2;
  unsigned short* Wtb   = (unsigned short*)w; w += (size_t)CD * IND * 2;
  unsigned short* Hb    = (unsigned short*)w; w += (size_t)NN * OD * 2;
  float* ssrc = (float*)w; w += (size_t)NN * NH * 4;
  float* sdst = (float*)w; w += (size_t)NN * NH * 4;
  float* se   = (float*)w; w += 64 * 4;
  int* cnt    = (int*)w; w += (size_t)NN * 4;
  int* cur    = (int*)w; w += (size_t)NN * 4;   // adjacent to cnt: one memset
  int* off    = (int*)w; w += (size_t)(NN + 1) * 4;
  int* packed = (int*)w; w += (size_t)NEDGE * 4;
  unsigned short* pw = (unsigned short*)w; w += (size_t)NEDGE * NH * 2;

  hipMemsetAsync(cnt, 0, (size_t)NN * 2 * 4, stream);

  k_cast_feat<<<(NN * IND / 4 + 255) / 256, 256, 0, stream>>>(feat, featb);
  k_cast_w<<<(CD * IND) / 256, 256, 0, stream>>>(Wfc, Wres, Wtb);
  dim3 gg((NN + 63) / 64, CD / 64);
  k_gemm<<<gg, 256, 0, stream>>>(featb, Wtb, bfc, bres, Hb, out);
  k_scores<<<NN, 256, 0, stream>>>(Hb, attn, ssrc, sdst);
  k_se<<<1, 256, 0, stream>>>(ee, attn, se);
  k_hist<<<(NEDGE + 255) / 256, 256, 0, stream>>>(dst, cnt);
  k_scan<<<1, 1024, 0, stream>>>(cnt, off);
  k_edge<<<(NEDGE + 255) / 256, 256, 0, stream>>>(src, dst, ety, ssrc, sdst, se,
                                                  off, cur, packed, pw);
  k_agg2<<<NN, 256, 0, stream>>>(Hb, off, packed, pw, out);
}

// Round 3
// 338.465 us; speedup vs baseline: 1.3359x; 1.1539x over previous
//
#include <hip/hip_runtime.h>
#include <hip/hip_bf16.h>
#include <cstdint>

#define NN 50000
#define NEDGE 800000
#define IND 256
#define NH 8
#define DHH 32
#define NET 8
#define LALPHA 0.2f
#define OD 256
#define CD 512

typedef __attribute__((ext_vector_type(8))) short short8;
typedef __attribute__((ext_vector_type(4))) float f32x4;

__device__ __forceinline__ unsigned short f2bf(float x) {
  union { float f; unsigned u; } v; v.f = x;
  unsigned r = v.u + 0x7FFFu + ((v.u >> 16) & 1u);
  return (unsigned short)(r >> 16);
}
__device__ __forceinline__ float bf2f(unsigned short u) {
  union { unsigned u; float f; } v; v.u = ((unsigned)u) << 16;
  return v.f;
}

// ---- build W^T concat (512 x 256 bf16) ----
__global__ __launch_bounds__(256) void k_cast_w(const float* __restrict__ Wfc,
                                                const float* __restrict__ Wres,
                                                unsigned short* __restrict__ Wtb) {
  int id = blockIdx.x * 256 + threadIdx.x;  // 512*256 threads
  int k = id >> 9;
  int c = id & 511;
  float v = (c < OD) ? Wfc[k * OD + c] : Wres[k * OD + (c - OD)];
  Wtb[(size_t)c * IND + k] = f2bf(v);
}

// ---- bf16 MFMA GEMM: A = feat f32 (cast in staging), Bt = [512 x 256] bf16 ----
__global__ __launch_bounds__(256) void k_gemm(const float* __restrict__ Af,
                                              const unsigned short* __restrict__ Bt,
                                              const float* __restrict__ bfc,
                                              const float* __restrict__ bres,
                                              unsigned short* __restrict__ Hb,
                                              float* __restrict__ R) {
  __shared__ unsigned short As[64][40];
  __shared__ unsigned short Bs[64][40];
  int bm = blockIdx.x, bn = blockIdx.y;
  int tid = threadIdx.x;
  int wave = tid >> 6, lane = tid & 63;
  int row0 = bm * 64, col0 = bn * 64;

  int ar = tid >> 2;
  int ak = (tid & 3) * 8;

  f32x4 acc[4];
#pragma unroll
  for (int i = 0; i < 4; ++i) acc[i] = (f32x4){0.f, 0.f, 0.f, 0.f};

  for (int k0 = 0; k0 < IND; k0 += 32) {
    int grow = row0 + ar;
    float4 f0 = {0.f, 0.f, 0.f, 0.f}, f1 = {0.f, 0.f, 0.f, 0.f};
    if (grow < NN) {
      f0 = *reinterpret_cast<const float4*>(Af + (size_t)grow * IND + k0 + ak);
      f1 = *reinterpret_cast<const float4*>(Af + (size_t)grow * IND + k0 + ak + 4);
    }
    unsigned short t8[8] = {f2bf(f0.x), f2bf(f0.y), f2bf(f0.z), f2bf(f0.w),
                            f2bf(f1.x), f2bf(f1.y), f2bf(f1.z), f2bf(f1.w)};
    *reinterpret_cast<short8*>(&As[ar][ak]) = *reinterpret_cast<short8*>(t8);
    short8 bv = *reinterpret_cast<const short8*>(Bt + (size_t)(col0 + ar) * IND + k0 + ak);
    *reinterpret_cast<short8*>(&Bs[ar][ak]) = bv;
    __syncthreads();
    short8 a = *reinterpret_cast<const short8*>(&As[wave * 16 + (lane & 15)][(lane >> 4) * 8]);
#pragma unroll
    for (int nf = 0; nf < 4; ++nf) {
      short8 b = *reinterpret_cast<const short8*>(&Bs[nf * 16 + (lane & 15)][(lane >> 4) * 8]);
      acc[nf] = __builtin_amdgcn_mfma_f32_16x16x32_bf16(a, b, acc[nf], 0, 0, 0);
    }
    __syncthreads();
  }

  int rl = wave * 16 + ((lane >> 4) * 4);
  int cl = lane & 15;
#pragma unroll
  for (int nf = 0; nf < 4; ++nf) {
    int gcol = col0 + nf * 16 + cl;
#pragma unroll
    for (int r = 0; r < 4; ++r) {
      int grow = row0 + rl + r;
      if (grow < NN) {
        float vv = acc[nf][r];
        if (gcol < OD) Hb[(size_t)grow * OD + gcol] = f2bf(vv + bfc[gcol]);
        else R[(size_t)grow * OD + (gcol - OD)] = vv + bres[gcol - OD];
      }
    }
  }
}

// ---- per-node attention scores (+ se computed by block 0) ----
__global__ __launch_bounds__(256) void k_scores(const unsigned short* __restrict__ Hb,
                                                const float* __restrict__ attn,
                                                const float* __restrict__ ee,
                                                float* __restrict__ ssrc,
                                                float* __restrict__ sdst,
                                                float* __restrict__ se) {
  int v = blockIdx.x, t = threadIdx.x;
  int h = t >> 5, d = t & 31;
  float val = bf2f(Hb[(size_t)v * OD + t]);
  float p1 = val * attn[h * 96 + d];
  float p2 = val * attn[h * 96 + 32 + d];
#pragma unroll
  for (int off = 16; off; off >>= 1) {
    p1 += __shfl_xor(p1, off, 32);
    p2 += __shfl_xor(p2, off, 32);
  }
  if (d == 0) { ssrc[v * NH + h] = p1; sdst[v * NH + h] = p2; }
  if (v == 0) {
    float ae = attn[h * 96 + 64 + d];
    for (int et = 0; et < NET; ++et) {
      float p = ee[et * OD + t] * ae;
#pragma unroll
      for (int off = 16; off; off >>= 1) p += __shfl_xor(p, off, 32);
      if (d == 0) se[et * NH + h] = p;
    }
  }
}

// ---- CSR build ----
__global__ __launch_bounds__(256) void k_hist(const int* __restrict__ dst, int* __restrict__ cnt) {
  int e = blockIdx.x * 256 + threadIdx.x;
  if (e < NEDGE) atomicAdd(&cnt[dst[e]], 1);
}

__global__ void k_scan(const int* __restrict__ cnt, int* __restrict__ off) {
  __shared__ int part[1024];
  int tid = threadIdx.x;
  const int chunk = (NN + 1023) / 1024;
  int s = tid * chunk, e = min(s + chunk, NN);
  int sum = 0;
  for (int i = s; i < e; ++i) sum += cnt[i];
  part[tid] = sum;
  __syncthreads();
  // Hillis-Steele inclusive scan over 1024 partials
  for (int dd = 1; dd < 1024; dd <<= 1) {
    int v = (tid >= dd) ? part[tid - dd] : 0;
    __syncthreads();
    part[tid] += v;
    __syncthreads();
  }
  int run = tid ? part[tid - 1] : 0;
  for (int i = s; i < e; ++i) { off[i] = run; run += cnt[i]; }
  if (tid == 1023) off[NN] = part[1023];
}

// ---- edge-parallel: CSR scatter + per-edge softmax numerators (8 heads, bf16) ----
__global__ __launch_bounds__(256) void k_edge(const int* __restrict__ src,
                                              const int* __restrict__ dst,
                                              const int* __restrict__ ety,
                                              const float* __restrict__ ssrc,
                                              const float* __restrict__ sdst,
                                              const float* __restrict__ se,
                                              const int* __restrict__ off,
                                              int* __restrict__ cur,
                                              int* __restrict__ packed,
                                              unsigned short* __restrict__ pw) {
  __shared__ float sse[64];
  int tid = threadIdx.x;
  if (tid < 64) sse[tid] = se[tid];
  __syncthreads();
  int e = blockIdx.x * 256 + tid;
  if (e >= NEDGE) return;
  int u = src[e], v = dst[e], et = ety[e];
  int pos = off[v] + atomicAdd(&cur[v], 1);
  packed[pos] = u;
  float4 a0 = *reinterpret_cast<const float4*>(ssrc + (size_t)u * NH);
  float4 a1 = *reinterpret_cast<const float4*>(ssrc + (size_t)u * NH + 4);
  float4 b0 = *reinterpret_cast<const float4*>(sdst + (size_t)v * NH);
  float4 b1 = *reinterpret_cast<const float4*>(sdst + (size_t)v * NH + 4);
  float sa[8] = {a0.x + b0.x, a0.y + b0.y, a0.z + b0.z, a0.w + b0.w,
                 a1.x + b1.x, a1.y + b1.y, a1.z + b1.z, a1.w + b1.w};
  ushort4 o0, o1;
  unsigned short w8[8];
#pragma unroll
  for (int h = 0; h < 8; ++h) {
    float s = sa[h] + sse[et * NH + h];
    s = s > 0.f ? s : LALPHA * s;
    w8[h] = f2bf(__expf(s));   // scores are O(2): exp safe without max-sub
  }
  o0.x = w8[0]; o0.y = w8[1]; o0.z = w8[2]; o0.w = w8[3];
  o1.x = w8[4]; o1.y = w8[5]; o1.z = w8[6]; o1.w = w8[7];
  *reinterpret_cast<ushort4*>(pw + (size_t)pos * NH) = o0;
  *reinterpret_cast<ushort4*>(pw + (size_t)pos * NH + 4) = o1;
}

// ---- per-node aggregation: 1 wave/node, 4 ch/lane, unroll x4 ----
__global__ __launch_bounds__(256) void k_agg2(const unsigned short* __restrict__ Hb,
                                              const int* __restrict__ off,
                                              const int* __restrict__ packed,
                                              const unsigned short* __restrict__ pw,
                                              float* __restrict__ out) {
  int v = blockIdx.x * 4 + (threadIdx.x >> 6);
  int lane = threadIdx.x & 63;
  if (v >= NN) return;
  int h = lane >> 3;                 // head of channels 4*lane .. 4*lane+3
  int lo = off[v], hi = off[v + 1];
  float a0 = 0.f, a1 = 0.f, a2 = 0.f, a3 = 0.f, dsum = 0.f;
  int i = lo;
  for (; i + 4 <= hi; i += 4) {
    int u0 = packed[i], u1 = packed[i + 1], u2 = packed[i + 2], u3 = packed[i + 3];
    float p0 = bf2f(pw[(size_t)i * NH + h]);
    float p1 = bf2f(pw[(size_t)(i + 1) * NH + h]);
    float p2 = bf2f(pw[(size_t)(i + 2) * NH + h]);
    float p3 = bf2f(pw[(size_t)(i + 3) * NH + h]);
    ushort4 x0 = *reinterpret_cast<const ushort4*>(Hb + (size_t)u0 * OD + lane * 4);
    ushort4 x1 = *reinterpret_cast<const ushort4*>(Hb + (size_t)u1 * OD + lane * 4);
    ushort4 x2 = *reinterpret_cast<const ushort4*>(Hb + (size_t)u2 * OD + lane * 4);
    ushort4 x3 = *reinterpret_cast<const ushort4*>(Hb + (size_t)u3 * OD + lane * 4);
    a0 = fmaf(p0, bf2f(x0.x), a0); a1 = fmaf(p0, bf2f(x0.y), a1);
    a2 = fmaf(p0, bf2f(x0.z), a2); a3 = fmaf(p0, bf2f(x0.w), a3);
    a0 = fmaf(p1, bf2f(x1.x), a0); a1 = fmaf(p1, bf2f(x1.y), a1);
    a2 = fmaf(p1, bf2f(x1.z), a2); a3 = fmaf(p1, bf2f(x1.w), a3);
    a0 = fmaf(p2, bf2f(x2.x), a0); a1 = fmaf(p2, bf2f(x2.y), a1);
    a2 = fmaf(p2, bf2f(x2.z), a2); a3 = fmaf(p2, bf2f(x2.w), a3);
    a0 = fmaf(p3, bf2f(x3.x), a0); a1 = fmaf(p3, bf2f(x3.y), a1);
    a2 = fmaf(p3, bf2f(x3.z), a2); a3 = fmaf(p3, bf2f(x3.w), a3);
    dsum += (p0 + p1) + (p2 + p3);
  }
  for (; i < hi; ++i) {
    int u0 = packed[i];
    float p0 = bf2f(pw[(size_t)i * NH + h]);
    ushort4 x0 = *reinterpret_cast<const ushort4*>(Hb + (size_t)u0 * OD + lane * 4);
    a0 = fmaf(p0, bf2f(x0.x), a0); a1 = fmaf(p0, bf2f(x0.y), a1);
    a2 = fmaf(p0, bf2f(x0.z), a2); a3 = fmaf(p0, bf2f(x0.w), a3);
    dsum += p0;
  }
  size_t oi = (size_t)v * OD + lane * 4;
  float4 r = *reinterpret_cast<const float4*>(out + oi);
  float inv = (dsum > 0.f) ? 1.f / dsum : 0.f;   // no edges -> acc=0 -> o=r
  float o0 = fmaf(a0, inv, r.x);
  float o1 = fmaf(a1, inv, r.y);
  float o2 = fmaf(a2, inv, r.z);
  float o3 = fmaf(a3, inv, r.w);
  float4 wv;
  wv.x = o0 > 0.f ? o0 : expm1f(o0);
  wv.y = o1 > 0.f ? o1 : expm1f(o1);
  wv.z = o2 > 0.f ? o2 : expm1f(o2);
  wv.w = o3 > 0.f ? o3 : expm1f(o3);
  *reinterpret_cast<float4*>(out + oi) = wv;
}

extern "C" void kernel_launch(void* const* d_in, const int* in_sizes, int n_in,
                              void* d_out, int out_size, void* d_ws, size_t ws_size,
                              hipStream_t stream) {
  const float* feat = (const float*)d_in[0];
  const int* src = (const int*)d_in[1];
  const int* dst = (const int*)d_in[2];
  const int* ety = (const int*)d_in[3];
  const float* Wfc = (const float*)d_in[4];
  const float* bfc = (const float*)d_in[5];
  const float* ee = (const float*)d_in[6];
  const float* attn = (const float*)d_in[7];
  const float* Wres = (const float*)d_in[8];
  const float* bres = (const float*)d_in[9];
  float* out = (float*)d_out;

  char* w = (char*)d_ws;
  unsigned short* Wtb   = (unsigned short*)w; w += (size_t)CD * IND * 2;
  unsigned short* Hb    = (unsigned short*)w; w += (size_t)NN * OD * 2;
  float* ssrc = (float*)w; w += (size_t)NN * NH * 4;
  float* sdst = (float*)w; w += (size_t)NN * NH * 4;
  float* se   = (float*)w; w += 64 * 4;
  int* cnt    = (int*)w; w += (size_t)NN * 4;
  int* cur    = (int*)w; w += (size_t)NN * 4;   // adjacent to cnt: one memset
  int* off    = (int*)w; w += (size_t)(NN + 1) * 4;
  int* packed = (int*)w; w += (size_t)NEDGE * 4;
  unsigned short* pw = (unsigned short*)w; w += (size_t)NEDGE * NH * 2;

  hipMemsetAsync(cnt, 0, (size_t)NN * 2 * 4, stream);

  k_cast_w<<<(CD * IND) / 256, 256, 0, stream>>>(Wfc, Wres, Wtb);
  dim3 gg((NN + 63) / 64, CD / 64);
  k_gemm<<<gg, 256, 0, stream>>>(feat, Wtb, bfc, bres, Hb, out);
  k_scores<<<NN, 256, 0, stream>>>(Hb, attn, ee, ssrc, sdst, se);
  k_hist<<<(NEDGE + 255) / 256, 256, 0, stream>>>(dst, cnt);
  k_scan<<<1, 1024, 0, stream>>>(cnt, off);
  k_edge<<<(NEDGE + 255) / 256, 256, 0, stream>>>(src, dst, ety, ssrc, sdst, se,
                                                  off, cur, packed, pw);
  k_agg2<<<NN / 4, 256, 0, stream>>>(Hb, off, packed, pw, out);
}

// Round 4
// 322.800 us; speedup vs baseline: 1.4007x; 1.0485x over previous
//
#include <hip/hip_runtime.h>
#include <hip/hip_bf16.h>
#include <cstdint>

#define NN 50000
#define NEDGE 800000
#define IND 256
#define NH 8
#define DHH 32
#define NET 8
#define LALPHA 0.2f
#define OD 256
#define CD 512

typedef __attribute__((ext_vector_type(8))) short short8;
typedef __attribute__((ext_vector_type(4))) float f32x4;

__device__ __forceinline__ unsigned short f2bf(float x) {
  union { float f; unsigned u; } v; v.f = x;
  unsigned r = v.u + 0x7FFFu + ((v.u >> 16) & 1u);
  return (unsigned short)(r >> 16);
}
__device__ __forceinline__ float bf2f(unsigned short u) {
  union { unsigned u; float f; } v; v.u = ((unsigned)u) << 16;
  return v.f;
}

// ---- build W^T concat (512 x 256 bf16) ----
__global__ __launch_bounds__(256) void k_cast_w(const float* __restrict__ Wfc,
                                                const float* __restrict__ Wres,
                                                unsigned short* __restrict__ Wtb) {
  int id = blockIdx.x * 256 + threadIdx.x;  // 512*256 threads
  int k = id >> 9;
  int c = id & 511;
  float v = (c < OD) ? Wfc[k * OD + c] : Wres[k * OD + (c - OD)];
  Wtb[(size_t)c * IND + k] = f2bf(v);
}

// ---- bf16 MFMA GEMM: 64-row panel per block, all 512 cols inside ----
// A staged once (f32->bf16), B tile restaged per 64-col stripe from L2-hot Wtb.
__global__ __launch_bounds__(256) void k_gemm(const float* __restrict__ Af,
                                              const unsigned short* __restrict__ Bt,
                                              const float* __restrict__ bfc,
                                              const float* __restrict__ bres,
                                              unsigned short* __restrict__ Hb,
                                              unsigned short* __restrict__ Rb) {
  __shared__ unsigned short As[64][264];   // 264: 528B row stride, 16B-aligned, ~2-way banks
  __shared__ unsigned short Bs[64][264];
  int tid = threadIdx.x;
  int wave = tid >> 6, lane = tid & 63;
  int row0 = blockIdx.x * 64;

  int ar = tid >> 2;          // 0..63
  int ac = (tid & 3) * 8;     // 0,8,16,24

  // stage full A panel: 64 rows x 256 k (f32 -> bf16)
#pragma unroll
  for (int j = 0; j < 8; ++j) {
    int k = j * 32 + ac;
    int grow = row0 + ar;
    float4 f0 = {0.f, 0.f, 0.f, 0.f}, f1 = {0.f, 0.f, 0.f, 0.f};
    if (grow < NN) {
      f0 = *reinterpret_cast<const float4*>(Af + (size_t)grow * IND + k);
      f1 = *reinterpret_cast<const float4*>(Af + (size_t)grow * IND + k + 4);
    }
    unsigned short t8[8] = {f2bf(f0.x), f2bf(f0.y), f2bf(f0.z), f2bf(f0.w),
                            f2bf(f1.x), f2bf(f1.y), f2bf(f1.z), f2bf(f1.w)};
    *reinterpret_cast<short8*>(&As[ar][k]) = *reinterpret_cast<short8*>(t8);
  }

  f32x4 acc[4];
#pragma unroll
  for (int i = 0; i < 4; ++i) acc[i] = (f32x4){0.f, 0.f, 0.f, 0.f};

  short8 areg[8];
  int arow = wave * 16 + (lane & 15);
  int akof = (lane >> 4) * 8;
  int rl = wave * 16 + ((lane >> 4) * 4);
  int cl = lane & 15;

  for (int bn = 0; bn < 8; ++bn) {
    if (bn) __syncthreads();            // previous Bs consumers done
    // stage B tile: 64 cols x 256 k
#pragma unroll
    for (int j = 0; j < 8; ++j) {
      int k = j * 32 + ac;
      short8 bv = *reinterpret_cast<const short8*>(Bt + (size_t)(bn * 64 + ar) * IND + k);
      *reinterpret_cast<short8*>(&Bs[ar][k]) = bv;
    }
    __syncthreads();                    // As (first iter) + Bs ready
    if (bn == 0) {
#pragma unroll
      for (int ks = 0; ks < 8; ++ks)
        areg[ks] = *reinterpret_cast<const short8*>(&As[arow][ks * 32 + akof]);
    }
#pragma unroll
    for (int ks = 0; ks < 8; ++ks) {
#pragma unroll
      for (int nf = 0; nf < 4; ++nf) {
        short8 b = *reinterpret_cast<const short8*>(&Bs[nf * 16 + (lane & 15)][ks * 32 + akof]);
        acc[nf] = __builtin_amdgcn_mfma_f32_16x16x32_bf16(areg[ks], b, acc[nf], 0, 0, 0);
      }
    }
    // epilogue for this 64-col stripe
#pragma unroll
    for (int nf = 0; nf < 4; ++nf) {
      int gcol = bn * 64 + nf * 16 + cl;
      float bias = (gcol < OD) ? bfc[gcol] : bres[gcol - OD];
#pragma unroll
      for (int r = 0; r < 4; ++r) {
        int grow = row0 + rl + r;
        if (grow < NN) {
          float vv = acc[nf][r] + bias;
          if (gcol < OD) Hb[(size_t)grow * OD + gcol] = f2bf(vv);
          else Rb[(size_t)grow * OD + (gcol - OD)] = f2bf(vv);
        }
      }
      acc[nf] = (f32x4){0.f, 0.f, 0.f, 0.f};
    }
  }
}

// ---- per-node attention scores (+ se computed by block 0) ----
__global__ __launch_bounds__(256) void k_scores(const unsigned short* __restrict__ Hb,
                                                const float* __restrict__ attn,
                                                const float* __restrict__ ee,
                                                float* __restrict__ ssrc,
                                                float* __restrict__ sdst,
                                                float* __restrict__ se) {
  int v = blockIdx.x, t = threadIdx.x;
  int h = t >> 5, d = t & 31;
  float val = bf2f(Hb[(size_t)v * OD + t]);
  float p1 = val * attn[h * 96 + d];
  float p2 = val * attn[h * 96 + 32 + d];
#pragma unroll
  for (int off = 16; off; off >>= 1) {
    p1 += __shfl_xor(p1, off, 32);
    p2 += __shfl_xor(p2, off, 32);
  }
  if (d == 0) { ssrc[v * NH + h] = p1; sdst[v * NH + h] = p2; }
  if (v == 0) {
    float ae = attn[h * 96 + 64 + d];
    for (int et = 0; et < NET; ++et) {
      float p = ee[et * OD + t] * ae;
#pragma unroll
      for (int off = 16; off; off >>= 1) p += __shfl_xor(p, off, 32);
      if (d == 0) se[et * NH + h] = p;
    }
  }
}

// ---- CSR build ----
__global__ __launch_bounds__(256) void k_hist(const int* __restrict__ dst, int* __restrict__ cnt) {
  int e = blockIdx.x * 256 + threadIdx.x;
  if (e < NEDGE) atomicAdd(&cnt[dst[e]], 1);
}

__global__ void k_scan(const int* __restrict__ cnt, int* __restrict__ off) {
  __shared__ int part[1024];
  int tid = threadIdx.x;
  const int chunk = (NN + 1023) / 1024;
  int s = tid * chunk, e = min(s + chunk, NN);
  int sum = 0;
  for (int i = s; i < e; ++i) sum += cnt[i];
  part[tid] = sum;
  __syncthreads();
  for (int dd = 1; dd < 1024; dd <<= 1) {
    int v = (tid >= dd) ? part[tid - dd] : 0;
    __syncthreads();
    part[tid] += v;
    __syncthreads();
  }
  int run = tid ? part[tid - 1] : 0;
  for (int i = s; i < e; ++i) { off[i] = run; run += cnt[i]; }
  if (tid == 1023) off[NN] = part[1023];
}

// ---- edge-parallel: CSR scatter + per-edge softmax numerators (8 heads, bf16) ----
__global__ __launch_bounds__(256) void k_edge(const int* __restrict__ src,
                                              const int* __restrict__ dst,
                                              const int* __restrict__ ety,
                                              const float* __restrict__ ssrc,
                                              const float* __restrict__ sdst,
                                              const float* __restrict__ se,
                                              const int* __restrict__ off,
                                              int* __restrict__ cur,
                                              int* __restrict__ packed,
                                              unsigned short* __restrict__ pw) {
  __shared__ float sse[64];
  int tid = threadIdx.x;
  if (tid < 64) sse[tid] = se[tid];
  __syncthreads();
  int e = blockIdx.x * 256 + tid;
  if (e >= NEDGE) return;
  int u = src[e], v = dst[e], et = ety[e];
  int pos = off[v] + atomicAdd(&cur[v], 1);
  packed[pos] = u;
  float4 a0 = *reinterpret_cast<const float4*>(ssrc + (size_t)u * NH);
  float4 a1 = *reinterpret_cast<const float4*>(ssrc + (size_t)u * NH + 4);
  float4 b0 = *reinterpret_cast<const float4*>(sdst + (size_t)v * NH);
  float4 b1 = *reinterpret_cast<const float4*>(sdst + (size_t)v * NH + 4);
  float sa[8] = {a0.x + b0.x, a0.y + b0.y, a0.z + b0.z, a0.w + b0.w,
                 a1.x + b1.x, a1.y + b1.y, a1.z + b1.z, a1.w + b1.w};
  ushort4 o0, o1;
  unsigned short w8[8];
#pragma unroll
  for (int h = 0; h < 8; ++h) {
    float s = sa[h] + sse[et * NH + h];
    s = s > 0.f ? s : LALPHA * s;
    w8[h] = f2bf(__expf(s));   // scores are O(2): exp safe without max-sub
  }
  o0.x = w8[0]; o0.y = w8[1]; o0.z = w8[2]; o0.w = w8[3];
  o1.x = w8[4]; o1.y = w8[5]; o1.z = w8[6]; o1.w = w8[7];
  *reinterpret_cast<ushort4*>(pw + (size_t)pos * NH) = o0;
  *reinterpret_cast<ushort4*>(pw + (size_t)pos * NH + 4) = o1;
}

// ---- per-node aggregation: 1 wave/node, 4 ch/lane, unroll x4 ----
__global__ __launch_bounds__(256) void k_agg2(const unsigned short* __restrict__ Hb,
                                              const unsigned short* __restrict__ Rb,
                                              const int* __restrict__ off,
                                              const int* __restrict__ packed,
                                              const unsigned short* __restrict__ pw,
                                              float* __restrict__ out) {
  int v = blockIdx.x * 4 + (threadIdx.x >> 6);
  int lane = threadIdx.x & 63;
  if (v >= NN) return;
  int h = lane >> 3;                 // head of channels 4*lane .. 4*lane+3
  int lo = off[v], hi = off[v + 1];
  float a0 = 0.f, a1 = 0.f, a2 = 0.f, a3 = 0.f, dsum = 0.f;
  int i = lo;
  for (; i + 4 <= hi; i += 4) {
    int u0 = packed[i], u1 = packed[i + 1], u2 = packed[i + 2], u3 = packed[i + 3];
    float p0 = bf2f(pw[(size_t)i * NH + h]);
    float p1 = bf2f(pw[(size_t)(i + 1) * NH + h]);
    float p2 = bf2f(pw[(size_t)(i + 2) * NH + h]);
    float p3 = bf2f(pw[(size_t)(i + 3) * NH + h]);
    ushort4 x0 = *reinterpret_cast<const ushort4*>(Hb + (size_t)u0 * OD + lane * 4);
    ushort4 x1 = *reinterpret_cast<const ushort4*>(Hb + (size_t)u1 * OD + lane * 4);
    ushort4 x2 = *reinterpret_cast<const ushort4*>(Hb + (size_t)u2 * OD + lane * 4);
    ushort4 x3 = *reinterpret_cast<const ushort4*>(Hb + (size_t)u3 * OD + lane * 4);
    a0 = fmaf(p0, bf2f(x0.x), a0); a1 = fmaf(p0, bf2f(x0.y), a1);
    a2 = fmaf(p0, bf2f(x0.z), a2); a3 = fmaf(p0, bf2f(x0.w), a3);
    a0 = fmaf(p1, bf2f(x1.x), a0); a1 = fmaf(p1, bf2f(x1.y), a1);
    a2 = fmaf(p1, bf2f(x1.z), a2); a3 = fmaf(p1, bf2f(x1.w), a3);
    a0 = fmaf(p2, bf2f(x2.x), a0); a1 = fmaf(p2, bf2f(x2.y), a1);
    a2 = fmaf(p2, bf2f(x2.z), a2); a3 = fmaf(p2, bf2f(x2.w), a3);
    a0 = fmaf(p3, bf2f(x3.x), a0); a1 = fmaf(p3, bf2f(x3.y), a1);
    a2 = fmaf(p3, bf2f(x3.z), a2); a3 = fmaf(p3, bf2f(x3.w), a3);
    dsum += (p0 + p1) + (p2 + p3);
  }
  for (; i < hi; ++i) {
    int u0 = packed[i];
    float p0 = bf2f(pw[(size_t)i * NH + h]);
    ushort4 x0 = *reinterpret_cast<const ushort4*>(Hb + (size_t)u0 * OD + lane * 4);
    a0 = fmaf(p0, bf2f(x0.x), a0); a1 = fmaf(p0, bf2f(x0.y), a1);
    a2 = fmaf(p0, bf2f(x0.z), a2); a3 = fmaf(p0, bf2f(x0.w), a3);
    dsum += p0;
  }
  size_t oi = (size_t)v * OD + lane * 4;
  ushort4 rv = *reinterpret_cast<const ushort4*>(Rb + oi);
  float inv = (dsum > 0.f) ? 1.f / dsum : 0.f;   // no edges -> acc=0 -> o=r
  float o0 = fmaf(a0, inv, bf2f(rv.x));
  float o1 = fmaf(a1, inv, bf2f(rv.y));
  float o2 = fmaf(a2, inv, bf2f(rv.z));
  float o3 = fmaf(a3, inv, bf2f(rv.w));
  float4 wv;
  wv.x = o0 > 0.f ? o0 : expm1f(o0);
  wv.y = o1 > 0.f ? o1 : expm1f(o1);
  wv.z = o2 > 0.f ? o2 : expm1f(o2);
  wv.w = o3 > 0.f ? o3 : expm1f(o3);
  *reinterpret_cast<float4*>(out + oi) = wv;
}

extern "C" void kernel_launch(void* const* d_in, const int* in_sizes, int n_in,
                              void* d_out, int out_size, void* d_ws, size_t ws_size,
                              hipStream_t stream) {
  const float* feat = (const float*)d_in[0];
  const int* src = (const int*)d_in[1];
  const int* dst = (const int*)d_in[2];
  const int* ety = (const int*)d_in[3];
  const float* Wfc = (const float*)d_in[4];
  const float* bfc = (const float*)d_in[5];
  const float* ee = (const float*)d_in[6];
  const float* attn = (const float*)d_in[7];
  const float* Wres = (const float*)d_in[8];
  const float* bres = (const float*)d_in[9];
  float* out = (float*)d_out;

  char* w = (char*)d_ws;
  unsigned short* Wtb   = (unsigned short*)w; w += (size_t)CD * IND * 2;
  unsigned short* Hb    = (unsigned short*)w; w += (size_t)NN * OD * 2;
  unsigned short* Rb    = (unsigned short*)w; w += (size_t)NN * OD * 2;
  float* ssrc = (float*)w; w += (size_t)NN * NH * 4;
  float* sdst = (float*)w; w += (size_t)NN * NH * 4;
  float* se   = (float*)w; w += 64 * 4;
  int* cnt    = (int*)w; w += (size_t)NN * 4;
  int* cur    = (int*)w; w += (size_t)NN * 4;   // adjacent to cnt: one memset
  int* off    = (int*)w; w += (size_t)(NN + 1) * 4;
  int* packed = (int*)w; w += (size_t)NEDGE * 4;
  unsigned short* pw = (unsigned short*)w; w += (size_t)NEDGE * NH * 2;

  hipMemsetAsync(cnt, 0, (size_t)NN * 2 * 4, stream);

  k_cast_w<<<(CD * IND) / 256, 256, 0, stream>>>(Wfc, Wres, Wtb);
  k_gemm<<<(NN + 63) / 64, 256, 0, stream>>>(feat, Wtb, bfc, bres, Hb, Rb);
  k_scores<<<NN, 256, 0, stream>>>(Hb, attn, ee, ssrc, sdst, se);
  k_hist<<<(NEDGE + 255) / 256, 256, 0, stream>>>(dst, cnt);
  k_scan<<<1, 1024, 0, stream>>>(cnt, off);
  k_edge<<<(NEDGE + 255) / 256, 256, 0, stream>>>(src, dst, ety, ssrc, sdst, se,
                                                  off, cur, packed, pw);
  k_agg2<<<NN / 4, 256, 0, stream>>>(Hb, Rb, off, packed, pw, out);
}

// Round 5
// 231.980 us; speedup vs baseline: 1.9491x; 1.3915x over previous
//
#include <hip/hip_runtime.h>
#include <hip/hip_bf16.h>
#include <cstdint>

#define NN 50000
#define NEDGE 800000
#define IND 256
#define NH 8
#define DHH 32
#define NET 8
#define LALPHA 0.2f
#define OD 256
#define CD 512
#define SCAN_BLOCKS 196   // 196*256 = 50176 >= NN+1

typedef __attribute__((ext_vector_type(8))) short short8;
typedef __attribute__((ext_vector_type(4))) float f32x4;

__device__ __forceinline__ unsigned short f2bf(float x) {
  union { float f; unsigned u; } v; v.f = x;
  unsigned r = v.u + 0x7FFFu + ((v.u >> 16) & 1u);
  return (unsigned short)(r >> 16);
}
__device__ __forceinline__ float bf2f(unsigned short u) {
  union { unsigned u; float f; } v; v.u = ((unsigned)u) << 16;
  return v.f;
}

// ---- build W^T concat (512 x 256 bf16) ----
__global__ __launch_bounds__(256) void k_cast_w(const float* __restrict__ Wfc,
                                                const float* __restrict__ Wres,
                                                unsigned short* __restrict__ Wtb) {
  int id = blockIdx.x * 256 + threadIdx.x;  // 512*256 threads
  int k = id >> 9;
  int c = id & 511;
  float v = (c < OD) ? Wfc[k * OD + c] : Wres[k * OD + (c - OD)];
  Wtb[(size_t)c * IND + k] = f2bf(v);
}

// ---- bf16 MFMA GEMM: A-frags in registers (f32 loads, cast in-reg), B stripe in LDS ----
// Each block: 64 rows; waves own 16 rows each. Loop 8 x 64-col stripes of Bt.
__global__ __launch_bounds__(256, 4) void k_gemm(const float* __restrict__ Af,
                                                 const unsigned short* __restrict__ Bt,
                                                 const float* __restrict__ bfc,
                                                 const float* __restrict__ bres,
                                                 unsigned short* __restrict__ Hb,
                                                 unsigned short* __restrict__ Rb) {
  __shared__ unsigned short Bs[64][264];   // 33.8 KB -> 4 blocks/CU
  int tid = threadIdx.x;
  int wave = tid >> 6, lane = tid & 63;
  int row0 = blockIdx.x * 64;

  int sr = tid >> 2;          // staging: col 0..63
  int sc = (tid & 3) * 8;     // k offset 0,8,16,24 (within 32-chunk)

  // load A fragments once: row = row0 + wave*16 + (lane&15), k = ks*32 + (lane>>4)*8
  int arow = row0 + wave * 16 + (lane & 15);
  int lrow = arow < NN ? arow : NN - 1;    // clamp loads; stores guarded
  int akof = (lane >> 4) * 8;
  short8 areg[8];
#pragma unroll
  for (int ks = 0; ks < 8; ++ks) {
    const float* p = Af + (size_t)lrow * IND + ks * 32 + akof;
    float4 f0 = *reinterpret_cast<const float4*>(p);
    float4 f1 = *reinterpret_cast<const float4*>(p + 4);
    unsigned short t8[8] = {f2bf(f0.x), f2bf(f0.y), f2bf(f0.z), f2bf(f0.w),
                            f2bf(f1.x), f2bf(f1.y), f2bf(f1.z), f2bf(f1.w)};
    areg[ks] = *reinterpret_cast<short8*>(t8);
  }

  int rl = wave * 16 + ((lane >> 4) * 4);
  int cl = lane & 15;

  for (int bn = 0; bn < 8; ++bn) {
    if (bn) __syncthreads();            // previous stripe consumers done
    // stage B stripe: 64 cols x 256 k (L2-hot source)
#pragma unroll
    for (int j = 0; j < 8; ++j) {
      int k = j * 32 + sc;
      short8 bv = *reinterpret_cast<const short8*>(Bt + (size_t)(bn * 64 + sr) * IND + k);
      *reinterpret_cast<short8*>(&Bs[sr][k]) = bv;
    }
    __syncthreads();

    f32x4 acc[4];
#pragma unroll
    for (int i = 0; i < 4; ++i) acc[i] = (f32x4){0.f, 0.f, 0.f, 0.f};
#pragma unroll
    for (int ks = 0; ks < 8; ++ks) {
#pragma unroll
      for (int nf = 0; nf < 4; ++nf) {
        short8 b = *reinterpret_cast<const short8*>(&Bs[nf * 16 + cl][ks * 32 + akof]);
        acc[nf] = __builtin_amdgcn_mfma_f32_16x16x32_bf16(areg[ks], b, acc[nf], 0, 0, 0);
      }
    }
    // epilogue for this 64-col stripe
#pragma unroll
    for (int nf = 0; nf < 4; ++nf) {
      int gcol = bn * 64 + nf * 16 + cl;
      float bias = (gcol < OD) ? bfc[gcol] : bres[gcol - OD];
#pragma unroll
      for (int r = 0; r < 4; ++r) {
        int grow = row0 + rl + r;
        if (grow < NN) {
          float vv = acc[nf][r] + bias;
          if (gcol < OD) Hb[(size_t)grow * OD + gcol] = f2bf(vv);
          else Rb[(size_t)grow * OD + (gcol - OD)] = f2bf(vv);
        }
      }
    }
  }
}

// ---- per-node attention scores (+ se computed by block 0) ----
__global__ __launch_bounds__(256) void k_scores(const unsigned short* __restrict__ Hb,
                                                const float* __restrict__ attn,
                                                const float* __restrict__ ee,
                                                float* __restrict__ ssrc,
                                                float* __restrict__ sdst,
                                                float* __restrict__ se) {
  int v = blockIdx.x, t = threadIdx.x;
  int h = t >> 5, d = t & 31;
  float val = bf2f(Hb[(size_t)v * OD + t]);
  float p1 = val * attn[h * 96 + d];
  float p2 = val * attn[h * 96 + 32 + d];
#pragma unroll
  for (int off = 16; off; off >>= 1) {
    p1 += __shfl_xor(p1, off, 32);
    p2 += __shfl_xor(p2, off, 32);
  }
  if (d == 0) { ssrc[v * NH + h] = p1; sdst[v * NH + h] = p2; }
  if (v == 0) {
    float ae = attn[h * 96 + 64 + d];
    for (int et = 0; et < NET; ++et) {
      float p = ee[et * OD + t] * ae;
#pragma unroll
      for (int off = 16; off; off >>= 1) p += __shfl_xor(p, off, 32);
      if (d == 0) se[et * NH + h] = p;
    }
  }
}

// ---- CSR build ----
__global__ __launch_bounds__(256) void k_hist(const int* __restrict__ dst, int* __restrict__ cnt) {
  int e = blockIdx.x * 256 + threadIdx.x;
  if (e < NEDGE) atomicAdd(&cnt[dst[e]], 1);
}

// phase A: per-block exclusive scan of 256 cnt entries; off[gi] = local exclusive
__global__ __launch_bounds__(256) void k_scanA(const int* __restrict__ cnt,
                                               int* __restrict__ off,
                                               int* __restrict__ bsum) {
  __shared__ int sh[256];
  int tid = threadIdx.x;
  int gi = blockIdx.x * 256 + tid;
  int c = (gi < NN) ? cnt[gi] : 0;
  sh[tid] = c;
  __syncthreads();
#pragma unroll
  for (int d = 1; d < 256; d <<= 1) {
    int v = (tid >= d) ? sh[tid - d] : 0;
    __syncthreads();
    sh[tid] += v;
    __syncthreads();
  }
  off[gi] = sh[tid] - c;                       // exclusive within block
  if (tid == 255) bsum[blockIdx.x] = sh[255];  // block total
}

// phase B: exclusive scan of block sums (196 values)
__global__ __launch_bounds__(256) void k_scanB(const int* __restrict__ bsum,
                                               int* __restrict__ boff) {
  __shared__ int sh[256];
  int tid = threadIdx.x;
  int c = (tid < SCAN_BLOCKS) ? bsum[tid] : 0;
  sh[tid] = c;
  __syncthreads();
#pragma unroll
  for (int d = 1; d < 256; d <<= 1) {
    int v = (tid >= d) ? sh[tid - d] : 0;
    __syncthreads();
    sh[tid] += v;
    __syncthreads();
  }
  boff[tid] = sh[tid] - c;
}

// ---- edge-parallel: CSR scatter + per-edge softmax numerators (8 heads, bf16) ----
__global__ __launch_bounds__(256) void k_edge(const int* __restrict__ src,
                                              const int* __restrict__ dst,
                                              const int* __restrict__ ety,
                                              const float* __restrict__ ssrc,
                                              const float* __restrict__ sdst,
                                              const float* __restrict__ se,
                                              const int* __restrict__ off,
                                              const int* __restrict__ boff,
                                              int* __restrict__ cur,
                                              int* __restrict__ packed,
                                              unsigned short* __restrict__ pw) {
  __shared__ float sse[64];
  int tid = threadIdx.x;
  if (tid < 64) sse[tid] = se[tid];
  __syncthreads();
  int e = blockIdx.x * 256 + tid;
  if (e >= NEDGE) return;
  int u = src[e], v = dst[e], et = ety[e];
  int pos = off[v] + boff[v >> 8] + atomicAdd(&cur[v], 1);
  packed[pos] = u;
  float4 a0 = *reinterpret_cast<const float4*>(ssrc + (size_t)u * NH);
  float4 a1 = *reinterpret_cast<const float4*>(ssrc + (size_t)u * NH + 4);
  float4 b0 = *reinterpret_cast<const float4*>(sdst + (size_t)v * NH);
  float4 b1 = *reinterpret_cast<const float4*>(sdst + (size_t)v * NH + 4);
  float sa[8] = {a0.x + b0.x, a0.y + b0.y, a0.z + b0.z, a0.w + b0.w,
                 a1.x + b1.x, a1.y + b1.y, a1.z + b1.z, a1.w + b1.w};
  ushort4 o0, o1;
  unsigned short w8[8];
#pragma unroll
  for (int h = 0; h < 8; ++h) {
    float s = sa[h] + sse[et * NH + h];
    s = s > 0.f ? s : LALPHA * s;
    w8[h] = f2bf(__expf(s));   // scores are O(2): exp safe without max-sub
  }
  o0.x = w8[0]; o0.y = w8[1]; o0.z = w8[2]; o0.w = w8[3];
  o1.x = w8[4]; o1.y = w8[5]; o1.z = w8[6]; o1.w = w8[7];
  *reinterpret_cast<ushort4*>(pw + (size_t)pos * NH) = o0;
  *reinterpret_cast<ushort4*>(pw + (size_t)pos * NH + 4) = o1;
}

// ---- per-node aggregation: 1 wave/node, 4 ch/lane, unroll x4 ----
__global__ __launch_bounds__(256) void k_agg2(const unsigned short* __restrict__ Hb,
                                              const unsigned short* __restrict__ Rb,
                                              const int* __restrict__ off,
                                              const int* __restrict__ boff,
                                              const int* __restrict__ packed,
                                              const unsigned short* __restrict__ pw,
                                              float* __restrict__ out) {
  int v = blockIdx.x * 4 + (threadIdx.x >> 6);
  int lane = threadIdx.x & 63;
  if (v >= NN) return;
  int h = lane >> 3;                 // head of channels 4*lane .. 4*lane+3
  int lo = off[v] + boff[v >> 8];
  int hi = off[v + 1] + boff[(v + 1) >> 8];
  float a0 = 0.f, a1 = 0.f, a2 = 0.f, a3 = 0.f, dsum = 0.f;
  int i = lo;
  for (; i + 4 <= hi; i += 4) {
    int u0 = packed[i], u1 = packed[i + 1], u2 = packed[i + 2], u3 = packed[i + 3];
    float p0 = bf2f(pw[(size_t)i * NH + h]);
    float p1 = bf2f(pw[(size_t)(i + 1) * NH + h]);
    float p2 = bf2f(pw[(size_t)(i + 2) * NH + h]);
    float p3 = bf2f(pw[(size_t)(i + 3) * NH + h]);
    ushort4 x0 = *reinterpret_cast<const ushort4*>(Hb + (size_t)u0 * OD + lane * 4);
    ushort4 x1 = *reinterpret_cast<const ushort4*>(Hb + (size_t)u1 * OD + lane * 4);
    ushort4 x2 = *reinterpret_cast<const ushort4*>(Hb + (size_t)u2 * OD + lane * 4);
    ushort4 x3 = *reinterpret_cast<const ushort4*>(Hb + (size_t)u3 * OD + lane * 4);
    a0 = fmaf(p0, bf2f(x0.x), a0); a1 = fmaf(p0, bf2f(x0.y), a1);
    a2 = fmaf(p0, bf2f(x0.z), a2); a3 = fmaf(p0, bf2f(x0.w), a3);
    a0 = fmaf(p1, bf2f(x1.x), a0); a1 = fmaf(p1, bf2f(x1.y), a1);
    a2 = fmaf(p1, bf2f(x1.z), a2); a3 = fmaf(p1, bf2f(x1.w), a3);
    a0 = fmaf(p2, bf2f(x2.x), a0); a1 = fmaf(p2, bf2f(x2.y), a1);
    a2 = fmaf(p2, bf2f(x2.z), a2); a3 = fmaf(p2, bf2f(x2.w), a3);
    a0 = fmaf(p3, bf2f(x3.x), a0); a1 = fmaf(p3, bf2f(x3.y), a1);
    a2 = fmaf(p3, bf2f(x3.z), a2); a3 = fmaf(p3, bf2f(x3.w), a3);
    dsum += (p0 + p1) + (p2 + p3);
  }
  for (; i < hi; ++i) {
    int u0 = packed[i];
    float p0 = bf2f(pw[(size_t)i * NH + h]);
    ushort4 x0 = *reinterpret_cast<const ushort4*>(Hb + (size_t)u0 * OD + lane * 4);
    a0 = fmaf(p0, bf2f(x0.x), a0); a1 = fmaf(p0, bf2f(x0.y), a1);
    a2 = fmaf(p0, bf2f(x0.z), a2); a3 = fmaf(p0, bf2f(x0.w), a3);
    dsum += p0;
  }
  size_t oi = (size_t)v * OD + lane * 4;
  ushort4 rv = *reinterpret_cast<const ushort4*>(Rb + oi);
  float inv = (dsum > 0.f) ? 1.f / dsum : 0.f;   // no edges -> acc=0 -> o=r
  float o0 = fmaf(a0, inv, bf2f(rv.x));
  float o1 = fmaf(a1, inv, bf2f(rv.y));
  float o2 = fmaf(a2, inv, bf2f(rv.z));
  float o3 = fmaf(a3, inv, bf2f(rv.w));
  float4 wv;
  wv.x = o0 > 0.f ? o0 : expm1f(o0);
  wv.y = o1 > 0.f ? o1 : expm1f(o1);
  wv.z = o2 > 0.f ? o2 : expm1f(o2);
  wv.w = o3 > 0.f ? o3 : expm1f(o3);
  *reinterpret_cast<float4*>(out + oi) = wv;
}

extern "C" void kernel_launch(void* const* d_in, const int* in_sizes, int n_in,
                              void* d_out, int out_size, void* d_ws, size_t ws_size,
                              hipStream_t stream) {
  const float* feat = (const float*)d_in[0];
  const int* src = (const int*)d_in[1];
  const int* dst = (const int*)d_in[2];
  const int* ety = (const int*)d_in[3];
  const float* Wfc = (const float*)d_in[4];
  const float* bfc = (const float*)d_in[5];
  const float* ee = (const float*)d_in[6];
  const float* attn = (const float*)d_in[7];
  const float* Wres = (const float*)d_in[8];
  const float* bres = (const float*)d_in[9];
  float* out = (float*)d_out;

  char* w = (char*)d_ws;
  unsigned short* Wtb   = (unsigned short*)w; w += (size_t)CD * IND * 2;
  unsigned short* Hb    = (unsigned short*)w; w += (size_t)NN * OD * 2;
  unsigned short* Rb    = (unsigned short*)w; w += (size_t)NN * OD * 2;
  float* ssrc = (float*)w; w += (size_t)NN * NH * 4;
  float* sdst = (float*)w; w += (size_t)NN * NH * 4;
  float* se   = (float*)w; w += 64 * 4;
  int* cnt    = (int*)w; w += (size_t)NN * 4;
  int* cur    = (int*)w; w += (size_t)NN * 4;   // adjacent to cnt: one memset
  int* off    = (int*)w; w += (size_t)(SCAN_BLOCKS * 256) * 4;
  int* bsum   = (int*)w; w += 256 * 4;
  int* boff   = (int*)w; w += 256 * 4;
  int* packed = (int*)w; w += (size_t)NEDGE * 4;
  unsigned short* pw = (unsigned short*)w; w += (size_t)NEDGE * NH * 2;

  hipMemsetAsync(cnt, 0, (size_t)NN * 2 * 4, stream);

  k_cast_w<<<(CD * IND) / 256, 256, 0, stream>>>(Wfc, Wres, Wtb);
  k_gemm<<<(NN + 63) / 64, 256, 0, stream>>>(feat, Wtb, bfc, bres, Hb, Rb);
  k_scores<<<NN, 256, 0, stream>>>(Hb, attn, ee, ssrc, sdst, se);
  k_hist<<<(NEDGE + 255) / 256, 256, 0, stream>>>(dst, cnt);
  k_scanA<<<SCAN_BLOCKS, 256, 0, stream>>>(cnt, off, bsum);
  k_scanB<<<1, 256, 0, stream>>>(bsum, boff);
  k_edge<<<(NEDGE + 255) / 256, 256, 0, stream>>>(src, dst, ety, ssrc, sdst, se,
                                                  off, boff, cur, packed, pw);
  k_agg2<<<NN / 4, 256, 0, stream>>>(Hb, Rb, off, boff, packed, pw, out);
}

// Round 6
// 214.246 us; speedup vs baseline: 2.1104x; 1.0828x over previous
//
#include <hip/hip_runtime.h>
#include <hip/hip_bf16.h>
#include <cstdint>

#define NN 50000
#define NEDGE 800000
#define IND 256
#define NH 8
#define DHH 32
#define NET 8
#define LALPHA 0.2f
#define OD 256
#define CD 512
#define SCAN_BLOCKS 196   // 196*256 = 50176 >= NN+1

typedef __attribute__((ext_vector_type(8))) short short8;
typedef __attribute__((ext_vector_type(4))) float f32x4;

__device__ __forceinline__ unsigned short f2bf(float x) {
  union { float f; unsigned u; } v; v.f = x;
  unsigned r = v.u + 0x7FFFu + ((v.u >> 16) & 1u);
  return (unsigned short)(r >> 16);
}
__device__ __forceinline__ float bf2f(unsigned short u) {
  union { unsigned u; float f; } v; v.u = ((unsigned)u) << 16;
  return v.f;
}
__device__ __forceinline__ float u2f_lo(unsigned w) {
  union { unsigned u; float f; } v; v.u = w << 16; return v.f;
}
__device__ __forceinline__ float u2f_hi(unsigned w) {
  union { unsigned u; float f; } v; v.u = w & 0xffff0000u; return v.f;
}

// ---- prep: W^T concat cast (512x256 bf16) + dst histogram ----
__global__ __launch_bounds__(256) void k_prep(const float* __restrict__ Wfc,
                                              const float* __restrict__ Wres,
                                              unsigned short* __restrict__ Wtb,
                                              const int* __restrict__ dst,
                                              int* __restrict__ cnt) {
  int id = blockIdx.x * 256 + threadIdx.x;   // grid covers NEDGE
  if (id < CD * IND) {
    int k = id >> 9;
    int c = id & 511;
    float v = (c < OD) ? Wfc[k * OD + c] : Wres[k * OD + (c - OD)];
    Wtb[(size_t)c * IND + k] = f2bf(v);
  }
  if (id < NEDGE) atomicAdd(&cnt[dst[id]], 1);
}

// ---- bf16 MFMA GEMM + fused attention scores ----
// A-frags in registers (f32 loads, cast in-reg), B stripe in LDS, 8 col stripes.
// For stripes 0..3 (h-part) also computes s_src/s_dst per (row, head) via
// width-16 shuffle reduction over the f32 (pre-bf16-round) outputs.
__global__ __launch_bounds__(256, 4) void k_gemm(const float* __restrict__ Af,
                                                 const unsigned short* __restrict__ Bt,
                                                 const float* __restrict__ bfc,
                                                 const float* __restrict__ bres,
                                                 const float* __restrict__ attn,
                                                 unsigned short* __restrict__ Hb,
                                                 unsigned short* __restrict__ Rb,
                                                 float* __restrict__ ssrc,
                                                 float* __restrict__ sdst) {
  __shared__ unsigned short Bs[64][264];   // 33.8 KB
  int tid = threadIdx.x;
  int wave = tid >> 6, lane = tid & 63;
  int row0 = blockIdx.x * 64;

  int sr = tid >> 2;          // staging: col 0..63
  int sc = (tid & 3) * 8;     // k offset

  int arow = row0 + wave * 16 + (lane & 15);
  int lrow = arow < NN ? arow : NN - 1;    // clamp loads; stores guarded
  int akof = (lane >> 4) * 8;
  short8 areg[8];
#pragma unroll
  for (int ks = 0; ks < 8; ++ks) {
    const float* p = Af + (size_t)lrow * IND + ks * 32 + akof;
    float4 f0 = *reinterpret_cast<const float4*>(p);
    float4 f1 = *reinterpret_cast<const float4*>(p + 4);
    unsigned short t8[8] = {f2bf(f0.x), f2bf(f0.y), f2bf(f0.z), f2bf(f0.w),
                            f2bf(f1.x), f2bf(f1.y), f2bf(f1.z), f2bf(f1.w)};
    areg[ks] = *reinterpret_cast<short8*>(t8);
  }

  int rl = wave * 16 + ((lane >> 4) * 4);
  int cl = lane & 15;

  for (int bn = 0; bn < 8; ++bn) {
    if (bn) __syncthreads();
#pragma unroll
    for (int j = 0; j < 8; ++j) {
      int k = j * 32 + sc;
      short8 bv = *reinterpret_cast<const short8*>(Bt + (size_t)(bn * 64 + sr) * IND + k);
      *reinterpret_cast<short8*>(&Bs[sr][k]) = bv;
    }
    __syncthreads();

    f32x4 acc[4];
#pragma unroll
    for (int i = 0; i < 4; ++i) acc[i] = (f32x4){0.f, 0.f, 0.f, 0.f};
#pragma unroll
    for (int ks = 0; ks < 8; ++ks) {
#pragma unroll
      for (int nf = 0; nf < 4; ++nf) {
        short8 b = *reinterpret_cast<const short8*>(&Bs[nf * 16 + cl][ks * 32 + akof]);
        acc[nf] = __builtin_amdgcn_mfma_f32_16x16x32_bf16(areg[ks], b, acc[nf], 0, 0, 0);
      }
    }

    bool isH = (bn < 4);
    float s0[4] = {0.f, 0.f, 0.f, 0.f}, s1[4] = {0.f, 0.f, 0.f, 0.f};
    float d0[4] = {0.f, 0.f, 0.f, 0.f}, d1[4] = {0.f, 0.f, 0.f, 0.f};
#pragma unroll
    for (int nf = 0; nf < 4; ++nf) {
      int gcol = bn * 64 + nf * 16 + cl;
      float bias = isH ? bfc[gcol] : bres[gcol - OD];
      float as_ = 0.f, ad_ = 0.f;
      if (isH) {
        int hh = gcol >> 5, dd = gcol & 31;
        as_ = attn[hh * 96 + dd];
        ad_ = attn[hh * 96 + 32 + dd];
      }
#pragma unroll
      for (int r = 0; r < 4; ++r) {
        int grow = row0 + rl + r;
        float vv = acc[nf][r] + bias;
        if (grow < NN) {
          if (isH) Hb[(size_t)grow * OD + gcol] = f2bf(vv);
          else Rb[(size_t)grow * OD + (gcol - OD)] = f2bf(vv);
        }
        if (isH) {
          if (nf < 2) { s0[r] = fmaf(vv, as_, s0[r]); d0[r] = fmaf(vv, ad_, d0[r]); }
          else        { s1[r] = fmaf(vv, as_, s1[r]); d1[r] = fmaf(vv, ad_, d1[r]); }
        }
      }
    }
    if (isH) {
      int h0 = 2 * bn, h1 = 2 * bn + 1;
#pragma unroll
      for (int r = 0; r < 4; ++r) {
        float vs0 = s0[r], vd0 = d0[r], vs1 = s1[r], vd1 = d1[r];
#pragma unroll
        for (int m = 8; m; m >>= 1) {
          vs0 += __shfl_xor(vs0, m, 16);
          vd0 += __shfl_xor(vd0, m, 16);
          vs1 += __shfl_xor(vs1, m, 16);
          vd1 += __shfl_xor(vd1, m, 16);
        }
        int grow = row0 + rl + r;
        if (cl == 0 && grow < NN) {
          ssrc[grow * NH + h0] = vs0;
          ssrc[grow * NH + h1] = vs1;
          sdst[grow * NH + h0] = vd0;
          sdst[grow * NH + h1] = vd1;
        }
      }
    }
  }
}

// phase A: per-block exclusive scan of 256 cnt entries
__global__ __launch_bounds__(256) void k_scanA(const int* __restrict__ cnt,
                                               int* __restrict__ off,
                                               int* __restrict__ bsum) {
  __shared__ int sh[256];
  int tid = threadIdx.x;
  int gi = blockIdx.x * 256 + tid;
  int c = (gi < NN) ? cnt[gi] : 0;
  sh[tid] = c;
  __syncthreads();
#pragma unroll
  for (int d = 1; d < 256; d <<= 1) {
    int v = (tid >= d) ? sh[tid - d] : 0;
    __syncthreads();
    sh[tid] += v;
    __syncthreads();
  }
  off[gi] = sh[tid] - c;
  if (tid == 255) bsum[blockIdx.x] = sh[255];
}

// phase B: exclusive scan of block sums + se[et,h]
__global__ __launch_bounds__(256) void k_scanB_se(const int* __restrict__ bsum,
                                                  int* __restrict__ boff,
                                                  const float* __restrict__ ee,
                                                  const float* __restrict__ attn,
                                                  float* __restrict__ se) {
  __shared__ int sh[256];
  int tid = threadIdx.x;
  int c = (tid < SCAN_BLOCKS) ? bsum[tid] : 0;
  sh[tid] = c;
  __syncthreads();
#pragma unroll
  for (int d = 1; d < 256; d <<= 1) {
    int v = (tid >= d) ? sh[tid - d] : 0;
    __syncthreads();
    sh[tid] += v;
    __syncthreads();
  }
  boff[tid] = sh[tid] - c;
  // se: tid = h*32 + d
  int h = tid >> 5, dd = tid & 31;
  float ae = attn[h * 96 + 64 + dd];
  for (int et = 0; et < NET; ++et) {
    float p = ee[et * OD + tid] * ae;
#pragma unroll
    for (int off2 = 16; off2; off2 >>= 1) p += __shfl_xor(p, off2, 32);
    if (dd == 0) se[et * NH + h] = p;
  }
}

// ---- edge-parallel: CSR scatter + per-edge softmax numerators (8 heads, bf16) ----
__global__ __launch_bounds__(256) void k_edge(const int* __restrict__ src,
                                              const int* __restrict__ dst,
                                              const int* __restrict__ ety,
                                              const float* __restrict__ ssrc,
                                              const float* __restrict__ sdst,
                                              const float* __restrict__ se,
                                              const int* __restrict__ off,
                                              const int* __restrict__ boff,
                                              int* __restrict__ cur,
                                              int* __restrict__ packed,
                                              unsigned short* __restrict__ pw) {
  __shared__ float sse[64];
  int tid = threadIdx.x;
  if (tid < 64) sse[tid] = se[tid];
  __syncthreads();
  int e = blockIdx.x * 256 + tid;
  if (e >= NEDGE) return;
  int u = src[e], v = dst[e], et = ety[e];
  int pos = off[v] + boff[v >> 8] + atomicAdd(&cur[v], 1);
  packed[pos] = u << 8;                       // u * OD: gather offset precomputed
  float4 a0 = *reinterpret_cast<const float4*>(ssrc + (size_t)u * NH);
  float4 a1 = *reinterpret_cast<const float4*>(ssrc + (size_t)u * NH + 4);
  float4 b0 = *reinterpret_cast<const float4*>(sdst + (size_t)v * NH);
  float4 b1 = *reinterpret_cast<const float4*>(sdst + (size_t)v * NH + 4);
  float sa[8] = {a0.x + b0.x, a0.y + b0.y, a0.z + b0.z, a0.w + b0.w,
                 a1.x + b1.x, a1.y + b1.y, a1.z + b1.z, a1.w + b1.w};
  ushort4 o0, o1;
  unsigned short w8[8];
#pragma unroll
  for (int h = 0; h < 8; ++h) {
    float s = sa[h] + sse[et * NH + h];
    s = s > 0.f ? s : LALPHA * s;
    w8[h] = f2bf(__expf(s));   // scores are O(2): exp safe without max-sub
  }
  o0.x = w8[0]; o0.y = w8[1]; o0.z = w8[2]; o0.w = w8[3];
  o1.x = w8[4]; o1.y = w8[5]; o1.z = w8[6]; o1.w = w8[7];
  *reinterpret_cast<ushort4*>(pw + (size_t)pos * NH) = o0;
  *reinterpret_cast<ushort4*>(pw + (size_t)pos * NH + 4) = o1;
}

// ---- per-node aggregation: 1 wave/node, 4 ch/lane, unroll x4, 32-bit offsets ----
__global__ __launch_bounds__(256) void k_agg2(const unsigned short* __restrict__ Hb,
                                              const unsigned short* __restrict__ Rb,
                                              const int* __restrict__ off,
                                              const int* __restrict__ boff,
                                              const int* __restrict__ packed,
                                              const unsigned short* __restrict__ pw,
                                              float* __restrict__ out) {
  int v = blockIdx.x * 4 + (threadIdx.x >> 6);
  int lane = threadIdx.x & 63;
  if (v >= NN) return;
  int h = lane >> 3;
  int lo = off[v] + boff[v >> 8];
  int hi = off[v + 1] + boff[(v + 1) >> 8];
  unsigned lane4 = (unsigned)(lane << 2);
  float a0 = 0.f, a1 = 0.f, a2 = 0.f, a3 = 0.f, dsum = 0.f;
  const unsigned short* pb = pw + (size_t)lo * NH + h;
  const int* pk = packed + lo;
  int n = hi - lo;
  int i = 0;
  for (; i + 4 <= n; i += 4) {
    unsigned o0 = (unsigned)pk[0] + lane4;
    unsigned o1 = (unsigned)pk[1] + lane4;
    unsigned o2 = (unsigned)pk[2] + lane4;
    unsigned o3 = (unsigned)pk[3] + lane4;
    float p0 = bf2f(pb[0]);
    float p1 = bf2f(pb[8]);
    float p2 = bf2f(pb[16]);
    float p3 = bf2f(pb[24]);
    uint2 x0 = *reinterpret_cast<const uint2*>(Hb + o0);
    uint2 x1 = *reinterpret_cast<const uint2*>(Hb + o1);
    uint2 x2 = *reinterpret_cast<const uint2*>(Hb + o2);
    uint2 x3 = *reinterpret_cast<const uint2*>(Hb + o3);
    a0 = fmaf(p0, u2f_lo(x0.x), a0); a1 = fmaf(p0, u2f_hi(x0.x), a1);
    a2 = fmaf(p0, u2f_lo(x0.y), a2); a3 = fmaf(p0, u2f_hi(x0.y), a3);
    a0 = fmaf(p1, u2f_lo(x1.x), a0); a1 = fmaf(p1, u2f_hi(x1.x), a1);
    a2 = fmaf(p1, u2f_lo(x1.y), a2); a3 = fmaf(p1, u2f_hi(x1.y), a3);
    a0 = fmaf(p2, u2f_lo(x2.x), a0); a1 = fmaf(p2, u2f_hi(x2.x), a1);
    a2 = fmaf(p2, u2f_lo(x2.y), a2); a3 = fmaf(p2, u2f_hi(x2.y), a3);
    a0 = fmaf(p3, u2f_lo(x3.x), a0); a1 = fmaf(p3, u2f_hi(x3.x), a1);
    a2 = fmaf(p3, u2f_lo(x3.y), a2); a3 = fmaf(p3, u2f_hi(x3.y), a3);
    dsum += (p0 + p1) + (p2 + p3);
    pk += 4; pb += 32;
  }
  for (; i < n; ++i) {
    unsigned o0 = (unsigned)pk[0] + lane4;
    float p0 = bf2f(pb[0]);
    uint2 x0 = *reinterpret_cast<const uint2*>(Hb + o0);
    a0 = fmaf(p0, u2f_lo(x0.x), a0); a1 = fmaf(p0, u2f_hi(x0.x), a1);
    a2 = fmaf(p0, u2f_lo(x0.y), a2); a3 = fmaf(p0, u2f_hi(x0.y), a3);
    dsum += p0;
    pk += 1; pb += 8;
  }
  unsigned oi32 = (unsigned)v * OD + lane4;
  uint2 rv = *reinterpret_cast<const uint2*>(Rb + oi32);
  float inv = (dsum > 0.f) ? 1.f / dsum : 0.f;   // no edges -> acc=0 -> o=r
  float o0 = fmaf(a0, inv, u2f_lo(rv.x));
  float o1 = fmaf(a1, inv, u2f_hi(rv.x));
  float o2 = fmaf(a2, inv, u2f_lo(rv.y));
  float o3 = fmaf(a3, inv, u2f_hi(rv.y));
  float4 wv;
  wv.x = o0 > 0.f ? o0 : expm1f(o0);
  wv.y = o1 > 0.f ? o1 : expm1f(o1);
  wv.z = o2 > 0.f ? o2 : expm1f(o2);
  wv.w = o3 > 0.f ? o3 : expm1f(o3);
  *reinterpret_cast<float4*>(out + (size_t)v * OD + lane4) = wv;
}

extern "C" void kernel_launch(void* const* d_in, const int* in_sizes, int n_in,
                              void* d_out, int out_size, void* d_ws, size_t ws_size,
                              hipStream_t stream) {
  const float* feat = (const float*)d_in[0];
  const int* src = (const int*)d_in[1];
  const int* dst = (const int*)d_in[2];
  const int* ety = (const int*)d_in[3];
  const float* Wfc = (const float*)d_in[4];
  const float* bfc = (const float*)d_in[5];
  const float* ee = (const float*)d_in[6];
  const float* attn = (const float*)d_in[7];
  const float* Wres = (const float*)d_in[8];
  const float* bres = (const float*)d_in[9];
  float* out = (float*)d_out;

  char* w = (char*)d_ws;
  unsigned short* Wtb   = (unsigned short*)w; w += (size_t)CD * IND * 2;
  unsigned short* Hb    = (unsigned short*)w; w += (size_t)NN * OD * 2;
  unsigned short* Rb    = (unsigned short*)w; w += (size_t)NN * OD * 2;
  float* ssrc = (float*)w; w += (size_t)NN * NH * 4;
  float* sdst = (float*)w; w += (size_t)NN * NH * 4;
  float* se   = (float*)w; w += 64 * 4;
  int* cnt    = (int*)w; w += (size_t)NN * 4;
  int* cur    = (int*)w; w += (size_t)NN * 4;   // adjacent to cnt: one memset
  int* off    = (int*)w; w += (size_t)(SCAN_BLOCKS * 256) * 4;
  int* bsum   = (int*)w; w += 256 * 4;
  int* boff   = (int*)w; w += 256 * 4;
  int* packed = (int*)w; w += (size_t)NEDGE * 4;
  unsigned short* pw = (unsigned short*)w; w += (size_t)NEDGE * NH * 2;

  hipMemsetAsync(cnt, 0, (size_t)NN * 2 * 4, stream);

  k_prep<<<(NEDGE + 255) / 256, 256, 0, stream>>>(Wfc, Wres, Wtb, dst, cnt);
  k_gemm<<<(NN + 63) / 64, 256, 0, stream>>>(feat, Wtb, bfc, bres, attn, Hb, Rb, ssrc, sdst);
  k_scanA<<<SCAN_BLOCKS, 256, 0, stream>>>(cnt, off, bsum);
  k_scanB_se<<<1, 256, 0, stream>>>(bsum, boff, ee, attn, se);
  k_edge<<<(NEDGE + 255) / 256, 256, 0, stream>>>(src, dst, ety, ssrc, sdst, se,
                                                  off, boff, cur, packed, pw);
  k_agg2<<<NN / 4, 256, 0, stream>>>(Hb, Rb, off, boff, packed, pw, out);
}